// Round 14
// baseline (371.486 us; speedup 1.0000x reference)
//
#include <hip/hip_runtime.h>
#include <hip/hip_bf16.h>
#include <stdint.h>

typedef __bf16 bf16_t;
typedef __bf16 bf16x8 __attribute__((ext_vector_type(8)));
typedef __bf16 bf16x4 __attribute__((ext_vector_type(4)));
typedef float f32x4 __attribute__((ext_vector_type(4)));

#define T_TOK 4096
#define DIM   1024
#define HID   2048
#define NE    8
#define MAXT  72   // max 128-row m-tiles: 8192/128 + 8

// async global->LDS, 16B per lane, LDS dest = wave-uniform base + lane*16
__device__ __forceinline__ void gload_lds16(const void* g, void* l) {
  __builtin_amdgcn_global_load_lds(
      (const __attribute__((address_space(1))) unsigned int*)g,
      (__attribute__((address_space(3))) unsigned int*)l, 16, 0, 0);
}

// ---------------- merged pre-pass: w12^T, w3^T, router(+x->bf16) in ONE launch ----------------
// bf16-in-LDS transpose, MLP=8: ALL 8 float4 loads issued into registers first
// (static-indexed v[8] -> stays in VGPRs), THEN convert + ds_write_b16 (2-way banks, free).
// phase2: ds_read_b128 + 16B coalesced store (256B runs).
__device__ __forceinline__ void wt_tile(const float* __restrict__ in,
                                        bf16_t* __restrict__ out,
                                        int K, int N, int e, int ky, int nx,
                                        bf16_t (*tileT)[129]) {
  const size_t eoff = (size_t)e * K * N;
  const int k0 = ky * 128, n0 = nx * 64;
  const int tid = threadIdx.x;
  const int kk = tid >> 4;          // 0..15
  const int n  = (tid & 15) * 4;    // 0..60
  const float* src = in + eoff + (size_t)(k0 + kk) * N + n0 + n;
  float4 v[8];
#pragma unroll
  for (int it = 0; it < 8; ++it)
    v[it] = *(const float4*)(src + (size_t)it * 16 * N);   // 8 independent loads in flight
#pragma unroll
  for (int it = 0; it < 8; ++it) {
    int k = kk + it * 16;
    tileT[n + 0][k] = (bf16_t)v[it].x;
    tileT[n + 1][k] = (bf16_t)v[it].y;
    tileT[n + 2][k] = (bf16_t)v[it].z;
    tileT[n + 3][k] = (bf16_t)v[it].w;
  }
  __syncthreads();
  bf16x8 o[4];
#pragma unroll
  for (int it = 0; it < 4; ++it) {
    int nn = (tid >> 4) + it * 16;
    int kc = (tid & 15) * 8;
    o[it] = *(const bf16x8*)(&tileT[nn][kc]);
  }
#pragma unroll
  for (int it = 0; it < 4; ++it) {
    int nn = (tid >> 4) + it * 16;
    int kc = (tid & 15) * 8;
    *(bf16x8*)(out + eoff + (size_t)(n0 + nn) * K + k0 + kc) = o[it];
  }
}

__global__ __launch_bounds__(256) void k_prep(
    const float* __restrict__ x, const float* __restrict__ rw,
    const float* __restrict__ rb, const float* __restrict__ w12,
    const float* __restrict__ w3, bf16_t* __restrict__ xb,
    bf16_t* __restrict__ w12t, bf16_t* __restrict__ w3t,
    int* __restrict__ counts, int* __restrict__ top_i, float* __restrict__ top_w,
    float* __restrict__ aux) {
  __shared__ bf16_t tileT[64][129];   // 16.5 KB (transpose branches only)
  const int b = blockIdx.x;
  if (b < 4096) {               // w12^T: K=1024 (8 k-tiles), N=4096 (64 n-tiles)
    int e = b >> 9, rem = b & 511;
    wt_tile(w12, w12t, DIM, 2 * HID, e, rem >> 6, rem & 63, tileT);
    return;
  }
  if (b < 6144) {               // w3^T: K=2048 (16 k-tiles), N=1024 (16 n-tiles)
    int lb = b - 4096;
    int e = lb >> 8, rem = lb & 255;
    wt_tile(w3, w3t, HID, DIM, e, rem >> 4, rem & 15, tileT);
    return;
  }
  // ---- router + x->bf16 ----
  int t = (b - 6144) * 4 + (threadIdx.x >> 6);
  int lane = threadIdx.x & 63;
  const float* xt = x + (size_t)t * DIM;
  float acc[8] = {0.f,0.f,0.f,0.f,0.f,0.f,0.f,0.f};
#pragma unroll
  for (int it = 0; it < 4; ++it) {
    int i = (it * 64 + lane) * 4;
    float4 xv = *(const float4*)(xt + i);
    bf16x4 o;
    o[0] = (bf16_t)xv.x; o[1] = (bf16_t)xv.y; o[2] = (bf16_t)xv.z; o[3] = (bf16_t)xv.w;
    *(bf16x4*)(xb + (size_t)t * DIM + i) = o;
#pragma unroll
    for (int c = 0; c < 4; ++c) {
      float v = (c == 0) ? xv.x : (c == 1) ? xv.y : (c == 2) ? xv.z : xv.w;
      float4 r0 = *(const float4*)(rw + (size_t)(i + c) * 8);
      float4 r1 = *(const float4*)(rw + (size_t)(i + c) * 8 + 4);
      acc[0] += v * r0.x; acc[1] += v * r0.y; acc[2] += v * r0.z; acc[3] += v * r0.w;
      acc[4] += v * r1.x; acc[5] += v * r1.y; acc[6] += v * r1.z; acc[7] += v * r1.w;
    }
  }
#pragma unroll
  for (int m = 32; m >= 1; m >>= 1) {
#pragma unroll
    for (int e = 0; e < 8; ++e) acc[e] += __shfl_xor(acc[e], m, 64);
  }
  if (lane == 0) {
    float s[8]; float sumsq = 0.f;
#pragma unroll
    for (int e = 0; e < 8; ++e) {
      float lg = acc[e] + rb[e];
      sumsq += lg * lg;
      s[e] = 1.f / (1.f + __expf(-lg));
    }
    int i1 = 0;
#pragma unroll
    for (int e = 1; e < 8; ++e) if (s[e] > s[i1]) i1 = e;
    int i2 = (i1 == 0) ? 1 : 0;
#pragma unroll
    for (int e = 0; e < 8; ++e) if (e != i1 && s[e] > s[i2]) i2 = e;
    float v1 = s[i1], v2 = s[i2];
    float den = v1 + v2 + 1e-6f;
    top_i[2 * t]     = i1; top_i[2 * t + 1] = i2;
    top_w[2 * t]     = v1 / den;
    top_w[2 * t + 1] = v2 / den;
    atomicAdd(&counts[i1], 1);
    atomicAdd(&counts[i2], 1);
    atomicAdd(aux, 0.01f * sumsq * (1.f / 32768.f));
  }
}

// ---------------- plan: base offsets + m-tile table ----------------
__global__ void k_plan(const int* __restrict__ counts, int* __restrict__ base,
                       int* __restrict__ tile_e, int* __restrict__ tile_m0) {
  if (threadIdx.x == 0) {
    int s = 0, nt = 0;
    for (int e = 0; e < NE; ++e) {
      base[e] = s;
      int c = counts[e];
      for (int m0 = 0; m0 < c; m0 += 128) { tile_e[nt] = e; tile_m0[nt] = m0; ++nt; }
      s += c;
    }
    for (; nt < MAXT; ++nt) tile_e[nt] = -1;
  }
}

// ---------------- gather tokens into per-expert slot lists ----------------
__global__ __launch_bounds__(256) void k_gather(const int* __restrict__ top_i,
    const float* __restrict__ top_w, const int* __restrict__ base,
    int* __restrict__ fill, int* __restrict__ slot_token, float* __restrict__ slot_wt,
    int* __restrict__ slot_of) {
  int t = blockIdx.x * 256 + threadIdx.x;
  if (t >= T_TOK) return;
#pragma unroll
  for (int j = 0; j < 2; ++j) {
    int e = top_i[2 * t + j];
    int p = atomicAdd(&fill[e], 1);
    int g = base[e] + p;
    slot_token[g] = t;
    slot_wt[g]    = top_w[2 * t + j];
    slot_of[2 * t + j] = g;
  }
}

// ---------------- GEMM1 + SwiGLU (proven R6/R8 optimum, unchanged) ----------------
__global__ __launch_bounds__(256) void k_gemm1(
    const bf16_t* __restrict__ xb, const bf16_t* __restrict__ w12t,
    const int* __restrict__ counts, const int* __restrict__ base,
    const int* __restrict__ tile_e, const int* __restrict__ tile_m0,
    const int* __restrict__ slot_token, bf16_t* __restrict__ h) {
  const int e = tile_e[blockIdx.y];
  if (e < 0) return;
  const int m0  = tile_m0[blockIdx.y];
  const int cnt = counts[e];
  const int bas = base[e];
  const int n0  = blockIdx.x * 64;          // hid col base, [0,2048)
  const bf16_t* W1 = w12t + (size_t)e * (4096u * 1024u) + (size_t)n0 * 1024u;
  const bf16_t* W2 = W1 + (size_t)2048 * 1024;

  __shared__ bf16_t sA[2][128 * 64];
  __shared__ bf16_t sB1[2][64 * 64];
  __shared__ bf16_t sB2[2][64 * 64];

  const int tid = threadIdx.x, lane = tid & 63, wid = tid >> 6;
  const int wr = wid >> 1, wc = wid & 1;
  const int lr = lane >> 3, sw = (lane & 7) ^ lr;  // swizzled source chunk

  int tokA[4];
#pragma unroll
  for (int i = 0; i < 4; ++i) {
    int row = m0 + wid * 32 + i * 8 + lr;
    tokA[i] = slot_token[bas + (row < cnt ? row : cnt - 1)];
  }

  auto stage = [&](int p, int k0) {
#pragma unroll
    for (int i = 0; i < 4; ++i)
      gload_lds16(xb + (size_t)tokA[i] * DIM + k0 + sw * 8,
                  &sA[p][(wid * 32 + i * 8) * 64]);
#pragma unroll
    for (int i = 0; i < 2; ++i) {
      int n = wid * 16 + i * 8 + lr;
      gload_lds16(W1 + (size_t)n * 1024 + k0 + sw * 8, &sB1[p][(wid * 16 + i * 8) * 64]);
      gload_lds16(W2 + (size_t)n * 1024 + k0 + sw * 8, &sB2[p][(wid * 16 + i * 8) * 64]);
    }
  };

  f32x4 acc1[4][2] = {};
  f32x4 acc2[4][2] = {};

  stage(0, 0);
  stage(1, 64);

  const int NT = DIM / 64;  // 16
  for (int t = 0; t < NT; ++t) {
    const int p = t & 1;
    if (t + 2 < NT) asm volatile("s_waitcnt vmcnt(8)" ::: "memory");
    else            asm volatile("s_waitcnt vmcnt(0)" ::: "memory");
    __builtin_amdgcn_s_barrier();
    asm volatile("" ::: "memory");
    __builtin_amdgcn_s_setprio(1);
#pragma unroll
    for (int kk = 0; kk < 2; ++kk) {
      const int g = kk * 4 + (lane >> 4);
      bf16x8 a[4], b1[2], b2[2];
#pragma unroll
      for (int mf = 0; mf < 4; ++mf) {
        int r = wr * 64 + mf * 16 + (lane & 15);
        a[mf] = *(const bf16x8*)(&sA[p][r * 64 + ((g ^ (r & 7)) << 3)]);
      }
#pragma unroll
      for (int nf = 0; nf < 2; ++nf) {
        int n = wc * 32 + nf * 16 + (lane & 15);
        b1[nf] = *(const bf16x8*)(&sB1[p][n * 64 + ((g ^ (n & 7)) << 3)]);
        b2[nf] = *(const bf16x8*)(&sB2[p][n * 64 + ((g ^ (n & 7)) << 3)]);
      }
#pragma unroll
      for (int mf = 0; mf < 4; ++mf)
#pragma unroll
        for (int nf = 0; nf < 2; ++nf) {
          acc1[mf][nf] = __builtin_amdgcn_mfma_f32_16x16x32_bf16(a[mf], b1[nf], acc1[mf][nf], 0, 0, 0);
          acc2[mf][nf] = __builtin_amdgcn_mfma_f32_16x16x32_bf16(a[mf], b2[nf], acc2[mf][nf], 0, 0, 0);
        }
    }
    __builtin_amdgcn_s_setprio(0);
    __builtin_amdgcn_sched_barrier(0);
    __builtin_amdgcn_s_barrier();
    asm volatile("" ::: "memory");
    if (t + 2 < NT) stage(p, (t + 2) * 64);
  }

#pragma unroll
  for (int mf = 0; mf < 4; ++mf)
#pragma unroll
    for (int r = 0; r < 4; ++r) {
      int m = wr * 64 + mf * 16 + ((lane >> 4) << 2) + r;
      if (m0 + m < cnt) {
        size_t rowoff = (size_t)(bas + m0 + m) * HID + n0;
#pragma unroll
        for (int nf = 0; nf < 2; ++nf) {
          int col = wc * 32 + nf * 16 + (lane & 15);
          float d1 = acc1[mf][nf][r], d2 = acc2[mf][nf][r];
          h[rowoff + col] = (bf16_t)((d1 / (1.f + __expf(-d1))) * d2);
        }
      }
    }
}

// ---------------- GEMM2: eout[slot] = wt * (h @ W3) (proven R8 form, unchanged) ----------------
__global__ __launch_bounds__(256) void k_gemm2(
    const bf16_t* __restrict__ h, const bf16_t* __restrict__ w3t,
    const int* __restrict__ counts, const int* __restrict__ base,
    const int* __restrict__ tile_e, const int* __restrict__ tile_m0,
    const float* __restrict__ slot_wt, bf16_t* __restrict__ eout) {
  const int e = tile_e[blockIdx.y];
  if (e < 0) return;
  const int m0  = tile_m0[blockIdx.y];
  const int cnt = counts[e];
  const int bas = base[e];
  const int n0 = blockIdx.x * 128;
  const bf16_t* W = w3t + (size_t)e * (1024u * 2048u);

  __shared__ bf16_t sA[2][128 * 64];
  __shared__ bf16_t sB[2][128 * 64];

  const int tid = threadIdx.x, lane = tid & 63, wid = tid >> 6;
  const int wr = wid >> 1, wc = wid & 1;
  const int lr = lane >> 3, sw = (lane & 7) ^ lr;

  int rowA[4];
#pragma unroll
  for (int i = 0; i < 4; ++i) {
    int row = m0 + wid * 32 + i * 8 + lr;
    rowA[i] = bas + (row < cnt ? row : cnt - 1);
  }

  auto stage = [&](int p, int k0) {
#pragma unroll
    for (int i = 0; i < 4; ++i) {
      int rr = wid * 32 + i * 8;
      gload_lds16(h + (size_t)rowA[i] * HID + k0 + sw * 8, &sA[p][rr * 64]);
      gload_lds16(W + (size_t)(n0 + rr + lr) * 2048 + k0 + sw * 8, &sB[p][rr * 64]);
    }
  };

  f32x4 acc[4][4] = {};

  stage(0, 0);
  stage(1, 64);

  const int NT = HID / 64;  // 32
  for (int t = 0; t < NT; ++t) {
    const int p = t & 1;
    if (t + 2 < NT) asm volatile("s_waitcnt vmcnt(8)" ::: "memory");
    else            asm volatile("s_waitcnt vmcnt(0)" ::: "memory");
    __builtin_amdgcn_s_barrier();
    asm volatile("" ::: "memory");
    __builtin_amdgcn_s_setprio(1);
#pragma unroll
    for (int kk = 0; kk < 2; ++kk) {
      const int g = kk * 4 + (lane >> 4);
      bf16x8 a[4], b[4];
#pragma unroll
      for (int mf = 0; mf < 4; ++mf) {
        int r = wr * 64 + mf * 16 + (lane & 15);
        a[mf] = *(const bf16x8*)(&sA[p][r * 64 + ((g ^ (r & 7)) << 3)]);
      }
#pragma unroll
      for (int nf = 0; nf < 4; ++nf) {
        int n = wc * 64 + nf * 16 + (lane & 15);
        b[nf] = *(const bf16x8*)(&sB[p][n * 64 + ((g ^ (n & 7)) << 3)]);
      }
#pragma unroll
      for (int mf = 0; mf < 4; ++mf)
#pragma unroll
        for (int nf = 0; nf < 4; ++nf)
          acc[mf][nf] = __builtin_amdgcn_mfma_f32_16x16x32_bf16(a[mf], b[nf], acc[mf][nf], 0, 0, 0);
    }
    __builtin_amdgcn_s_setprio(0);
    __builtin_amdgcn_sched_barrier(0);
    __builtin_amdgcn_s_barrier();
    asm volatile("" ::: "memory");
    if (t + 2 < NT) stage(p, (t + 2) * 64);
  }

#pragma unroll
  for (int mf = 0; mf < 4; ++mf)
#pragma unroll
    for (int r = 0; r < 4; ++r) {
      int m = wr * 64 + mf * 16 + ((lane >> 4) << 2) + r;
      if (m0 + m < cnt) {
        int gs = bas + m0 + m;
        float wt = slot_wt[gs];
        size_t o = (size_t)gs * DIM + n0;
#pragma unroll
        for (int nf = 0; nf < 4; ++nf) {
          int col = wc * 64 + nf * 16 + (lane & 15);
          eout[o + col] = (bf16_t)(acc[mf][nf][r] * wt);
        }
      }
    }
}

// ---------------- combine: out[t] = eout[g0] + eout[g1] ----------------
__global__ __launch_bounds__(256) void k_combine(const bf16_t* __restrict__ eout,
    const int* __restrict__ slot_of, float* __restrict__ out) {
  const int t = blockIdx.x;
  const int c = threadIdx.x * 4;
  const int g0 = slot_of[2 * t], g1 = slot_of[2 * t + 1];
  bf16x4 a = *(const bf16x4*)(eout + (size_t)g0 * DIM + c);
  bf16x4 b = *(const bf16x4*)(eout + (size_t)g1 * DIM + c);
  float4 o;
  o.x = (float)a[0] + (float)b[0];
  o.y = (float)a[1] + (float)b[1];
  o.z = (float)a[2] + (float)b[2];
  o.w = (float)a[3] + (float)b[3];
  *(float4*)(out + (size_t)t * DIM + c) = o;
}

extern "C" void kernel_launch(void* const* d_in, const int* in_sizes, int n_in,
                              void* d_out, int out_size, void* d_ws, size_t ws_size,
                              hipStream_t stream) {
  const float* x   = (const float*)d_in[0];
  const float* rw  = (const float*)d_in[1];
  const float* rb  = (const float*)d_in[2];
  const float* w12 = (const float*)d_in[3];
  const float* w3  = (const float*)d_in[4];
  float* out = (float*)d_out;
  float* aux = out + (size_t)T_TOK * DIM;

  char* ws = (char*)d_ws;
  int*   counts     = (int*)(ws + 0);
  int*   fill       = (int*)(ws + 64);
  int*   base       = (int*)(ws + 128);
  int*   top_i      = (int*)(ws + 4096);
  float* top_w      = (float*)(ws + 4096 + 32768);
  int*   slot_token = (int*)(ws + 4096 + 65536);
  float* slot_wt    = (float*)(ws + 4096 + 98304);
  int*   slot_of    = (int*)(ws + 4096 + 131072);
  int*   tile_e     = (int*)(ws + 4096 + 163840);
  int*   tile_m0    = (int*)(ws + 4096 + 164352);
  bf16_t* xb        = (bf16_t*)(ws + 262144);                       // 8 MiB
  bf16_t* h         = (bf16_t*)(ws + 262144 + 8388608);             // 32 MiB
  bf16_t* w12t      = (bf16_t*)(ws + 262144 + 8388608 + 33554432);  // 64 MiB
  bf16_t* w3t       = (bf16_t*)((char*)w12t + 67108864);            // 32 MiB
  bf16_t* eout      = w12t;  // aliases w12t region during gemm2 (w12t dead by then)
  // peak ws usage = 142,868,480 B — identical to R2's proven-safe footprint

  hipMemsetAsync(ws, 0, 256, stream);                 // counts/fill
  hipMemsetAsync(aux, 0, sizeof(float), stream);      // aux accumulator

  // merged independent pre-work: w12^T (4096 blocks) + w3^T (2048) + router (1024)
  k_prep<<<dim3(7168), dim3(256), 0, stream>>>(x, rw, rb, w12, w3, xb, w12t, w3t,
                                               counts, top_i, top_w, aux);
  k_plan<<<dim3(1), dim3(64), 0, stream>>>(counts, base, tile_e, tile_m0);
  k_gather<<<dim3(T_TOK / 256), dim3(256), 0, stream>>>(top_i, top_w, base, fill,
                                                        slot_token, slot_wt, slot_of);
  k_gemm1<<<dim3(HID / 64, MAXT), dim3(256), 0, stream>>>(
      xb, w12t, counts, base, tile_e, tile_m0, slot_token, h);
  k_gemm2<<<dim3(DIM / 128, MAXT), dim3(256), 0, stream>>>(
      h, w3t, counts, base, tile_e, tile_m0, slot_wt, eout);
  k_combine<<<dim3(T_TOK), dim3(256), 0, stream>>>(eout, slot_of, out);
}

// Round 15
// 369.362 us; speedup vs baseline: 1.0057x; 1.0057x over previous
//
#include <hip/hip_runtime.h>
#include <hip/hip_bf16.h>
#include <stdint.h>

typedef __bf16 bf16_t;
typedef __bf16 bf16x8 __attribute__((ext_vector_type(8)));
typedef __bf16 bf16x4 __attribute__((ext_vector_type(4)));
typedef float f32x4 __attribute__((ext_vector_type(4)));

#define T_TOK 4096
#define DIM   1024
#define HID   2048
#define NE    8
#define MAXT  72   // max 128-row m-tiles: 8192/128 + 8

// async global->LDS, 16B per lane, LDS dest = wave-uniform base + lane*16
__device__ __forceinline__ void gload_lds16(const void* g, void* l) {
  __builtin_amdgcn_global_load_lds(
      (const __attribute__((address_space(1))) unsigned int*)g,
      (__attribute__((address_space(3))) unsigned int*)l, 16, 0, 0);
}

// bf16-in-LDS transpose tile: [128 k][64 n] f32 -> out[n][k] bf16.
__device__ __forceinline__ void wt_tile(const float* __restrict__ in,
                                        bf16_t* __restrict__ out,
                                        int K, int N, int e, int ky, int nx,
                                        bf16_t (*tileT)[129]) {
  const size_t eoff = (size_t)e * K * N;
  const int k0 = ky * 128, n0 = nx * 64;
  const int tid = threadIdx.x;
#pragma unroll
  for (int it = 0; it < 8; ++it) {
    int k = (tid >> 4) + it * 16;
    int n = (tid & 15) * 4;
    float4 v = *(const float4*)(in + eoff + (size_t)(k0 + k) * N + n0 + n);
    tileT[n + 0][k] = (bf16_t)v.x;
    tileT[n + 1][k] = (bf16_t)v.y;
    tileT[n + 2][k] = (bf16_t)v.z;
    tileT[n + 3][k] = (bf16_t)v.w;
  }
  __syncthreads();
#pragma unroll
  for (int it = 0; it < 4; ++it) {
    int n = (tid >> 4) + it * 16;
    int kc = (tid & 15) * 8;
    bf16x8 o = *(const bf16x8*)(&tileT[n][kc]);
    *(bf16x8*)(out + eoff + (size_t)(n0 + n) * K + k0 + kc) = o;
  }
}

// ---------------- pre-pass: w12^T + router(+x->bf16). (w3^T moved into gemm1 launch) ----------------
__global__ __launch_bounds__(256) void k_prep(
    const float* __restrict__ x, const float* __restrict__ rw,
    const float* __restrict__ rb, const float* __restrict__ w12,
    bf16_t* __restrict__ xb, bf16_t* __restrict__ w12t,
    int* __restrict__ counts, int* __restrict__ top_i, float* __restrict__ top_w,
    float* __restrict__ aux) {
  __shared__ bf16_t tileT[64][129];   // 16.5 KB
  const int b = blockIdx.x;
  if (b < 4096) {               // w12^T: K=1024 (8 k-tiles), N=4096 (64 n-tiles)
    int e = b >> 9, rem = b & 511;
    wt_tile(w12, w12t, DIM, 2 * HID, e, rem >> 6, rem & 63, tileT);
    return;
  }
  // ---- router + x->bf16 ----
  int t = (b - 4096) * 4 + (threadIdx.x >> 6);
  int lane = threadIdx.x & 63;
  const float* xt = x + (size_t)t * DIM;
  float acc[8] = {0.f,0.f,0.f,0.f,0.f,0.f,0.f,0.f};
#pragma unroll
  for (int it = 0; it < 4; ++it) {
    int i = (it * 64 + lane) * 4;
    float4 xv = *(const float4*)(xt + i);
    bf16x4 o;
    o[0] = (bf16_t)xv.x; o[1] = (bf16_t)xv.y; o[2] = (bf16_t)xv.z; o[3] = (bf16_t)xv.w;
    *(bf16x4*)(xb + (size_t)t * DIM + i) = o;
#pragma unroll
    for (int c = 0; c < 4; ++c) {
      float v = (c == 0) ? xv.x : (c == 1) ? xv.y : (c == 2) ? xv.z : xv.w;
      float4 r0 = *(const float4*)(rw + (size_t)(i + c) * 8);
      float4 r1 = *(const float4*)(rw + (size_t)(i + c) * 8 + 4);
      acc[0] += v * r0.x; acc[1] += v * r0.y; acc[2] += v * r0.z; acc[3] += v * r0.w;
      acc[4] += v * r1.x; acc[5] += v * r1.y; acc[6] += v * r1.z; acc[7] += v * r1.w;
    }
  }
#pragma unroll
  for (int m = 32; m >= 1; m >>= 1) {
#pragma unroll
    for (int e = 0; e < 8; ++e) acc[e] += __shfl_xor(acc[e], m, 64);
  }
  if (lane == 0) {
    float s[8]; float sumsq = 0.f;
#pragma unroll
    for (int e = 0; e < 8; ++e) {
      float lg = acc[e] + rb[e];
      sumsq += lg * lg;
      s[e] = 1.f / (1.f + __expf(-lg));
    }
    int i1 = 0;
#pragma unroll
    for (int e = 1; e < 8; ++e) if (s[e] > s[i1]) i1 = e;
    int i2 = (i1 == 0) ? 1 : 0;
#pragma unroll
    for (int e = 0; e < 8; ++e) if (e != i1 && s[e] > s[i2]) i2 = e;
    float v1 = s[i1], v2 = s[i2];
    float den = v1 + v2 + 1e-6f;
    top_i[2 * t]     = i1; top_i[2 * t + 1] = i2;
    top_w[2 * t]     = v1 / den;
    top_w[2 * t + 1] = v2 / den;
    atomicAdd(&counts[i1], 1);
    atomicAdd(&counts[i2], 1);
    atomicAdd(aux, 0.01f * sumsq * (1.f / 32768.f));
  }
}

// ---------------- plan: base offsets + m-tile table ----------------
__global__ void k_plan(const int* __restrict__ counts, int* __restrict__ base,
                       int* __restrict__ tile_e, int* __restrict__ tile_m0) {
  if (threadIdx.x == 0) {
    int s = 0, nt = 0;
    for (int e = 0; e < NE; ++e) {
      base[e] = s;
      int c = counts[e];
      for (int m0 = 0; m0 < c; m0 += 128) { tile_e[nt] = e; tile_m0[nt] = m0; ++nt; }
      s += c;
    }
    for (; nt < MAXT; ++nt) tile_e[nt] = -1;
  }
}

// ---------------- gather tokens into per-expert slot lists ----------------
__global__ __launch_bounds__(256) void k_gather(const int* __restrict__ top_i,
    const float* __restrict__ top_w, const int* __restrict__ base,
    int* __restrict__ fill, int* __restrict__ slot_token, float* __restrict__ slot_wt,
    int* __restrict__ slot_of) {
  int t = blockIdx.x * 256 + threadIdx.x;
  if (t >= T_TOK) return;
#pragma unroll
  for (int j = 0; j < 2; ++j) {
    int e = top_i[2 * t + j];
    int p = atomicAdd(&fill[e], 1);
    int g = base[e] + p;
    slot_token[g] = t;
    slot_wt[g]    = top_w[2 * t + j];
    slot_of[2 * t + j] = g;
  }
}

// ---------------- GEMM1 + SwiGLU, with w3^T co-scheduled in the same launch ----------------
// grid = (32, 64 + MAXT). y<64: w3-transpose tile (dispatched first, overlaps gemm tiles).
// y>=64: proven R6/R8 gemm1 (128m x 64n x 2 panels, dbuf 64 KB, vmcnt(8) pipeline).
__global__ __launch_bounds__(256) void k_gemm1(
    const bf16_t* __restrict__ xb, const bf16_t* __restrict__ w12t,
    const float* __restrict__ w3, bf16_t* __restrict__ w3t,
    const int* __restrict__ counts, const int* __restrict__ base,
    const int* __restrict__ tile_e, const int* __restrict__ tile_m0,
    const int* __restrict__ slot_token, bf16_t* __restrict__ h) {
  __shared__ bf16_t sA[2][128 * 64];
  __shared__ bf16_t sB1[2][64 * 64];
  __shared__ bf16_t sB2[2][64 * 64];

  if (blockIdx.y < 64) {        // w3^T: 2048 tiles (K=2048: 16 k-tiles, N=1024: 16 n-tiles, 8 e)
    int id = blockIdx.y * 32 + blockIdx.x;
    int e = id >> 8, rem = id & 255;
    wt_tile(w3, w3t, HID, DIM, e, rem >> 4, rem & 15,
            (bf16_t(*)[129])&sA[0][0]);
    return;
  }

  const int ty = blockIdx.y - 64;
  const int e = tile_e[ty];
  if (e < 0) return;
  const int m0  = tile_m0[ty];
  const int cnt = counts[e];
  const int bas = base[e];
  const int n0  = blockIdx.x * 64;          // hid col base, [0,2048)
  const bf16_t* W1 = w12t + (size_t)e * (4096u * 1024u) + (size_t)n0 * 1024u;
  const bf16_t* W2 = W1 + (size_t)2048 * 1024;

  const int tid = threadIdx.x, lane = tid & 63, wid = tid >> 6;
  const int wr = wid >> 1, wc = wid & 1;
  const int lr = lane >> 3, sw = (lane & 7) ^ lr;  // swizzled source chunk

  int tokA[4];
#pragma unroll
  for (int i = 0; i < 4; ++i) {
    int row = m0 + wid * 32 + i * 8 + lr;
    tokA[i] = slot_token[bas + (row < cnt ? row : cnt - 1)];
  }

  auto stage = [&](int p, int k0) {
#pragma unroll
    for (int i = 0; i < 4; ++i)
      gload_lds16(xb + (size_t)tokA[i] * DIM + k0 + sw * 8,
                  &sA[p][(wid * 32 + i * 8) * 64]);
#pragma unroll
    for (int i = 0; i < 2; ++i) {
      int n = wid * 16 + i * 8 + lr;
      gload_lds16(W1 + (size_t)n * 1024 + k0 + sw * 8, &sB1[p][(wid * 16 + i * 8) * 64]);
      gload_lds16(W2 + (size_t)n * 1024 + k0 + sw * 8, &sB2[p][(wid * 16 + i * 8) * 64]);
    }
  };

  f32x4 acc1[4][2] = {};
  f32x4 acc2[4][2] = {};

  stage(0, 0);
  stage(1, 64);

  const int NT = DIM / 64;  // 16
  for (int t = 0; t < NT; ++t) {
    const int p = t & 1;
    if (t + 2 < NT) asm volatile("s_waitcnt vmcnt(8)" ::: "memory");
    else            asm volatile("s_waitcnt vmcnt(0)" ::: "memory");
    __builtin_amdgcn_s_barrier();
    asm volatile("" ::: "memory");
    __builtin_amdgcn_s_setprio(1);
#pragma unroll
    for (int kk = 0; kk < 2; ++kk) {
      const int g = kk * 4 + (lane >> 4);
      bf16x8 a[4], b1[2], b2[2];
#pragma unroll
      for (int mf = 0; mf < 4; ++mf) {
        int r = wr * 64 + mf * 16 + (lane & 15);
        a[mf] = *(const bf16x8*)(&sA[p][r * 64 + ((g ^ (r & 7)) << 3)]);
      }
#pragma unroll
      for (int nf = 0; nf < 2; ++nf) {
        int n = wc * 32 + nf * 16 + (lane & 15);
        b1[nf] = *(const bf16x8*)(&sB1[p][n * 64 + ((g ^ (n & 7)) << 3)]);
        b2[nf] = *(const bf16x8*)(&sB2[p][n * 64 + ((g ^ (n & 7)) << 3)]);
      }
#pragma unroll
      for (int mf = 0; mf < 4; ++mf)
#pragma unroll
        for (int nf = 0; nf < 2; ++nf) {
          acc1[mf][nf] = __builtin_amdgcn_mfma_f32_16x16x32_bf16(a[mf], b1[nf], acc1[mf][nf], 0, 0, 0);
          acc2[mf][nf] = __builtin_amdgcn_mfma_f32_16x16x32_bf16(a[mf], b2[nf], acc2[mf][nf], 0, 0, 0);
        }
    }
    __builtin_amdgcn_s_setprio(0);
    __builtin_amdgcn_sched_barrier(0);
    __builtin_amdgcn_s_barrier();
    asm volatile("" ::: "memory");
    if (t + 2 < NT) stage(p, (t + 2) * 64);
  }

#pragma unroll
  for (int mf = 0; mf < 4; ++mf)
#pragma unroll
    for (int r = 0; r < 4; ++r) {
      int m = wr * 64 + mf * 16 + ((lane >> 4) << 2) + r;
      if (m0 + m < cnt) {
        size_t rowoff = (size_t)(bas + m0 + m) * HID + n0;
#pragma unroll
        for (int nf = 0; nf < 2; ++nf) {
          int col = wc * 32 + nf * 16 + (lane & 15);
          float d1 = acc1[mf][nf][r], d2 = acc2[mf][nf][r];
          h[rowoff + col] = (bf16_t)((d1 / (1.f + __expf(-d1))) * d2);
        }
      }
    }
}

// ---------------- GEMM2: eout[slot] = wt * (h @ W3) (proven R8 form, unchanged) ----------------
__global__ __launch_bounds__(256) void k_gemm2(
    const bf16_t* __restrict__ h, const bf16_t* __restrict__ w3t,
    const int* __restrict__ counts, const int* __restrict__ base,
    const int* __restrict__ tile_e, const int* __restrict__ tile_m0,
    const float* __restrict__ slot_wt, bf16_t* __restrict__ eout) {
  const int e = tile_e[blockIdx.y];
  if (e < 0) return;
  const int m0  = tile_m0[blockIdx.y];
  const int cnt = counts[e];
  const int bas = base[e];
  const int n0 = blockIdx.x * 128;
  const bf16_t* W = w3t + (size_t)e * (1024u * 2048u);

  __shared__ bf16_t sA[2][128 * 64];
  __shared__ bf16_t sB[2][128 * 64];

  const int tid = threadIdx.x, lane = tid & 63, wid = tid >> 6;
  const int wr = wid >> 1, wc = wid & 1;
  const int lr = lane >> 3, sw = (lane & 7) ^ lr;

  int rowA[4];
#pragma unroll
  for (int i = 0; i < 4; ++i) {
    int row = m0 + wid * 32 + i * 8 + lr;
    rowA[i] = bas + (row < cnt ? row : cnt - 1);
  }

  auto stage = [&](int p, int k0) {
#pragma unroll
    for (int i = 0; i < 4; ++i) {
      int rr = wid * 32 + i * 8;
      gload_lds16(h + (size_t)rowA[i] * HID + k0 + sw * 8, &sA[p][rr * 64]);
      gload_lds16(W + (size_t)(n0 + rr + lr) * 2048 + k0 + sw * 8, &sB[p][rr * 64]);
    }
  };

  f32x4 acc[4][4] = {};

  stage(0, 0);
  stage(1, 64);

  const int NT = HID / 64;  // 32
  for (int t = 0; t < NT; ++t) {
    const int p = t & 1;
    if (t + 2 < NT) asm volatile("s_waitcnt vmcnt(8)" ::: "memory");
    else            asm volatile("s_waitcnt vmcnt(0)" ::: "memory");
    __builtin_amdgcn_s_barrier();
    asm volatile("" ::: "memory");
    __builtin_amdgcn_s_setprio(1);
#pragma unroll
    for (int kk = 0; kk < 2; ++kk) {
      const int g = kk * 4 + (lane >> 4);
      bf16x8 a[4], b[4];
#pragma unroll
      for (int mf = 0; mf < 4; ++mf) {
        int r = wr * 64 + mf * 16 + (lane & 15);
        a[mf] = *(const bf16x8*)(&sA[p][r * 64 + ((g ^ (r & 7)) << 3)]);
      }
#pragma unroll
      for (int nf = 0; nf < 4; ++nf) {
        int n = wc * 64 + nf * 16 + (lane & 15);
        b[nf] = *(const bf16x8*)(&sB[p][n * 64 + ((g ^ (n & 7)) << 3)]);
      }
#pragma unroll
      for (int mf = 0; mf < 4; ++mf)
#pragma unroll
        for (int nf = 0; nf < 4; ++nf)
          acc[mf][nf] = __builtin_amdgcn_mfma_f32_16x16x32_bf16(a[mf], b[nf], acc[mf][nf], 0, 0, 0);
    }
    __builtin_amdgcn_s_setprio(0);
    __builtin_amdgcn_sched_barrier(0);
    __builtin_amdgcn_s_barrier();
    asm volatile("" ::: "memory");
    if (t + 2 < NT) stage(p, (t + 2) * 64);
  }

#pragma unroll
  for (int mf = 0; mf < 4; ++mf)
#pragma unroll
    for (int r = 0; r < 4; ++r) {
      int m = wr * 64 + mf * 16 + ((lane >> 4) << 2) + r;
      if (m0 + m < cnt) {
        int gs = bas + m0 + m;
        float wt = slot_wt[gs];
        size_t o = (size_t)gs * DIM + n0;
#pragma unroll
        for (int nf = 0; nf < 4; ++nf) {
          int col = wc * 64 + nf * 16 + (lane & 15);
          eout[o + col] = (bf16_t)(acc[mf][nf][r] * wt);
        }
      }
    }
}

// ---------------- combine: out[t] = eout[g0] + eout[g1] ----------------
__global__ __launch_bounds__(256) void k_combine(const bf16_t* __restrict__ eout,
    const int* __restrict__ slot_of, float* __restrict__ out) {
  const int t = blockIdx.x;
  const int c = threadIdx.x * 4;
  const int g0 = slot_of[2 * t], g1 = slot_of[2 * t + 1];
  bf16x4 a = *(const bf16x4*)(eout + (size_t)g0 * DIM + c);
  bf16x4 b = *(const bf16x4*)(eout + (size_t)g1 * DIM + c);
  float4 o;
  o.x = (float)a[0] + (float)b[0];
  o.y = (float)a[1] + (float)b[1];
  o.z = (float)a[2] + (float)b[2];
  o.w = (float)a[3] + (float)b[3];
  *(float4*)(out + (size_t)t * DIM + c) = o;
}

extern "C" void kernel_launch(void* const* d_in, const int* in_sizes, int n_in,
                              void* d_out, int out_size, void* d_ws, size_t ws_size,
                              hipStream_t stream) {
  const float* x   = (const float*)d_in[0];
  const float* rw  = (const float*)d_in[1];
  const float* rb  = (const float*)d_in[2];
  const float* w12 = (const float*)d_in[3];
  const float* w3  = (const float*)d_in[4];
  float* out = (float*)d_out;
  float* aux = out + (size_t)T_TOK * DIM;

  char* ws = (char*)d_ws;
  int*   counts     = (int*)(ws + 0);
  int*   fill       = (int*)(ws + 64);
  int*   base       = (int*)(ws + 128);
  int*   top_i      = (int*)(ws + 4096);
  float* top_w      = (float*)(ws + 4096 + 32768);
  int*   slot_token = (int*)(ws + 4096 + 65536);
  float* slot_wt    = (float*)(ws + 4096 + 98304);
  int*   slot_of    = (int*)(ws + 4096 + 131072);
  int*   tile_e     = (int*)(ws + 4096 + 163840);
  int*   tile_m0    = (int*)(ws + 4096 + 164352);
  bf16_t* xb        = (bf16_t*)(ws + 262144);                       // 8 MiB
  bf16_t* h         = (bf16_t*)(ws + 262144 + 8388608);             // 32 MiB
  bf16_t* w12t      = (bf16_t*)(ws + 262144 + 8388608 + 33554432);  // 64 MiB
  bf16_t* w3t       = (bf16_t*)((char*)w12t + 67108864);            // 32 MiB
  bf16_t* eout      = w12t;  // aliases w12t region during gemm2 (w12t dead by then)
  // peak ws usage = 142,868,480 B — identical to R12-R14 proven-safe footprint

  hipMemsetAsync(ws, 0, 256, stream);                 // counts/fill
  hipMemsetAsync(aux, 0, sizeof(float), stream);      // aux accumulator

  // pre-work: w12^T (4096 blocks) + router (1024).  w3^T rides inside gemm1's launch.
  k_prep<<<dim3(5120), dim3(256), 0, stream>>>(x, rw, rb, w12, xb, w12t,
                                               counts, top_i, top_w, aux);
  k_plan<<<dim3(1), dim3(64), 0, stream>>>(counts, base, tile_e, tile_m0);
  k_gather<<<dim3(T_TOK / 256), dim3(256), 0, stream>>>(top_i, top_w, base, fill,
                                                        slot_token, slot_wt, slot_of);
  // y<64: w3^T tiles (2048); y>=64: gemm1 m-tiles
  k_gemm1<<<dim3(HID / 64, 64 + MAXT), dim3(256), 0, stream>>>(
      xb, w12t, w3, w3t, counts, base, tile_e, tile_m0, slot_token, h);
  k_gemm2<<<dim3(DIM / 128, MAXT), dim3(256), 0, stream>>>(
      h, w3t, counts, base, tile_e, tile_m0, slot_wt, eout);
  k_combine<<<dim3(T_TOK), dim3(256), 0, stream>>>(eout, slot_of, out);
}